// Round 1
// baseline (4691.373 us; speedup 1.0000x reference)
//
#include <hip/hip_runtime.h>
#include <math.h>

#define NN 20000
#define NE 320000
#define FD 256
#define AVG_LOG_F 2.83321334f
#define MT_NODES 157  // ceil(20000/128)

struct GemmSegs {
  const float* ptr[16];
  int stride[16];
  int mode[16];  // 0: 1.0, 1: f1=logd/AVG, 2: f2=AVG/logd
};

// ---------------- CSR build ----------------
__global__ __launch_bounds__(256) void k_count(const int* __restrict__ dst,
                                               int* __restrict__ deg, int E) {
  int e = blockIdx.x * 256 + threadIdx.x;
  if (e < E) atomicAdd(&deg[dst[e]], 1);
}

__global__ __launch_bounds__(1024) void k_scan(const int* __restrict__ deg,
                                               int* __restrict__ rp, int N) {
  __shared__ int lds[1024];
  int t = threadIdx.x;
  int CH = (N + 1023) >> 10;
  int base = t * CH;
  int s = 0;
  for (int i = 0; i < CH; ++i) { int idx = base + i; if (idx < N) s += deg[idx]; }
  lds[t] = s;
  __syncthreads();
  for (int off = 1; off < 1024; off <<= 1) {
    int v = (t >= off) ? lds[t - off] : 0;
    __syncthreads();
    lds[t] += v;
    __syncthreads();
  }
  int run = (t == 0) ? 0 : lds[t - 1];
  for (int i = 0; i < CH; ++i) {
    int idx = base + i;
    if (idx < N) { rp[idx] = run; run += deg[idx]; }
  }
  if (t == 1023) rp[N] = run;
}

__global__ __launch_bounds__(256) void k_scatter(const int* __restrict__ src,
                                                 const int* __restrict__ dst,
                                                 const int* __restrict__ rp,
                                                 int* __restrict__ cur,
                                                 int* __restrict__ col, int E) {
  int e = blockIdx.x * 256 + threadIdx.x;
  if (e < E) {
    int d = dst[e];
    int p = atomicAdd(&cur[d], 1);
    col[rp[d] + p] = src[e];
  }
}

// ---------------- aggregation (per node, stats of B over in-edges) ----------------
__global__ __launch_bounds__(256) void k_aggregate(
    const float* __restrict__ A, const float* __restrict__ B,
    const int* __restrict__ rp, const int* __restrict__ col,
    float* __restrict__ agg, float* __restrict__ scal) {
  int n = blockIdx.x;
  int f = threadIdx.x;
  int beg = rp[n], end = rp[n + 1];
  int deg = end - beg;
  float sb = 0.f, qb = 0.f;
  float mnb = 3.402823466e38f, mxb = -3.402823466e38f;
  for (int i = beg; i < end; ++i) {
    int s = col[i];
    float b = B[(size_t)s * FD + f];
    sb += b;
    qb = fmaf(b, b, qb);
    mnb = fminf(mnb, b);
    mxb = fmaxf(mxb, b);
  }
  float c = A[(size_t)n * FD + f];
  float degf = (float)deg;
  float degc = degf > 1.f ? degf : 1.f;
  float inv = 1.f / degc;
  float s_m = fmaf(degf, c, sb);             // deg*c + sum(B)
  float mean = s_m * inv;
  float mean2 = fmaf(degf * c, c, fmaf(2.f * c, sb, qb)) * inv;
  float var = mean2 - mean * mean;
  if (var < 0.f) var = 0.f;
  float sd = sqrtf(var + 1e-5f);
  float mn = deg > 0 ? c + mnb : 0.f;
  float mx = deg > 0 ? c + mxb : 0.f;
  size_t base = (size_t)n * 1280 + f;
  agg[base] = mean;
  agg[base + 256] = s_m;
  agg[base + 512] = sd;
  agg[base + 768] = mn;
  agg[base + 1024] = mx;
  if (f == 0) {
    float logd = logf(degc + 1.f);
    scal[2 * n] = logd / AVG_LOG_F;
    scal[2 * n + 1] = AVG_LOG_F / logd;
  }
}

// ---------------- generic segmented-input fp32 GEMM ----------------
// out[m][n] = sum_k v[m][k] * Welem(n,k) (+bias[n]) (opt relu)
// v[m][k]: seg = k>>8; v = segs.ptr[seg][m*stride + (k&255)] * scale(m, mode)
// Welem(n,k) = wtrans ? W[(woff+k)*wstride + n] : W[n*wstride + woff + k]
__global__ __launch_bounds__(256) void k_gemm(
    GemmSegs segs, const float* __restrict__ scal,
    const float* __restrict__ W, int wstride, int woff, int wtrans,
    const float* __restrict__ bias, float* __restrict__ out,
    int M, int Nout, int K, int relu) {
  __shared__ float As[16][128];
  __shared__ float Bs[16][128];
  const int m0 = blockIdx.y * 128;
  const int n0 = blockIdx.x * 128;
  const int tid = threadIdx.x;
  const int tx = tid & 15, ty = tid >> 4;
  const int lr = tid >> 2;
  const int lk = (tid & 3) << 2;
  float acc[8][8];
#pragma unroll
  for (int i = 0; i < 8; ++i)
#pragma unroll
    for (int j = 0; j < 8; ++j) acc[i][j] = 0.f;

  for (int k0 = 0; k0 < K; k0 += 16) {
    int kg = k0 + lk;
    int seg = kg >> 8;
    const float* sp = segs.ptr[seg];
    const int sstr = segs.stride[seg];
    const int md = segs.mode[seg];
    const int kin = kg & 255;
#pragma unroll
    for (int h = 0; h < 2; ++h) {
      int m = m0 + lr + h * 64;
      int mc = m < M ? m : M - 1;
      float4 v = *(const float4*)(sp + (size_t)mc * sstr + kin);
      if (md) {
        float sc = scal[mc * 2 + (md - 1)];
        v.x *= sc; v.y *= sc; v.z *= sc; v.w *= sc;
      }
      int r = lr + h * 64;
      As[lk + 0][r] = v.x;
      As[lk + 1][r] = v.y;
      As[lk + 2][r] = v.z;
      As[lk + 3][r] = v.w;
    }
    if (!wtrans) {
#pragma unroll
      for (int h = 0; h < 2; ++h) {
        int r = lr + h * 64;
        float4 v = *(const float4*)(W + (size_t)(n0 + r) * wstride + woff + k0 + lk);
        Bs[lk + 0][r] = v.x;
        Bs[lk + 1][r] = v.y;
        Bs[lk + 2][r] = v.z;
        Bs[lk + 3][r] = v.w;
      }
    } else {
      int kk = tid >> 5;
      int j = (tid & 31) << 2;
#pragma unroll
      for (int h = 0; h < 2; ++h) {
        float4 v = *(const float4*)(W + (size_t)(woff + k0 + kk + h * 8) * wstride + n0 + j);
        *(float4*)&Bs[kk + h * 8][j] = v;
      }
    }
    __syncthreads();
#pragma unroll
    for (int kk = 0; kk < 16; ++kk) {
      float a[8], b[8];
      *(float4*)&a[0] = *(const float4*)&As[kk][ty * 8];
      *(float4*)&a[4] = *(const float4*)&As[kk][ty * 8 + 4];
      *(float4*)&b[0] = *(const float4*)&Bs[kk][tx * 8];
      *(float4*)&b[4] = *(const float4*)&Bs[kk][tx * 8 + 4];
#pragma unroll
      for (int i = 0; i < 8; ++i)
#pragma unroll
        for (int j = 0; j < 8; ++j) acc[i][j] = fmaf(a[i], b[j], acc[i][j]);
    }
    __syncthreads();
  }
  float bi[8];
#pragma unroll
  for (int j = 0; j < 8; ++j) bi[j] = bias ? bias[n0 + tx * 8 + j] : 0.f;
#pragma unroll
  for (int i = 0; i < 8; ++i) {
    int m = m0 + ty * 8 + i;
    if (m < M) {
      float v[8];
#pragma unroll
      for (int j = 0; j < 8; ++j) {
        float t = acc[i][j] + bi[j];
        v[j] = (relu && t < 0.f) ? 0.f : t;
      }
      float* op = out + (size_t)m * Nout + n0 + tx * 8;
      *(float4*)op = make_float4(v[0], v[1], v[2], v[3]);
      *((float4*)op + 1) = make_float4(v[4], v[5], v[6], v[7]);
    }
  }
}

// bf = Wlin @ bpost + blin
__global__ __launch_bounds__(256) void k_bfuse(const float* __restrict__ Wlin,
                                               const float* __restrict__ bpost,
                                               const float* __restrict__ blin,
                                               float* __restrict__ bf) {
  __shared__ float bp[256];
  int t = threadIdx.x;
  bp[t] = bpost[t];
  __syncthreads();
  float s = blin[t];
  for (int k = 0; k < 256; ++k) s = fmaf(Wlin[t * 256 + k], bp[k], s);
  bf[t] = s;
}

// out[n] = dot(x[n], Wout) + bout
__global__ __launch_bounds__(256) void k_wout(const float* __restrict__ x,
                                              const float* __restrict__ w,
                                              const float* __restrict__ b,
                                              float* __restrict__ out, int N) {
  int wid = threadIdx.x >> 6, lane = threadIdx.x & 63;
  int n = blockIdx.x * 4 + wid;
  if (n >= N) return;
  const float4 xv = *(const float4*)(x + (size_t)n * FD + lane * 4);
  const float4 wv = *(const float4*)(w + lane * 4);
  float s = xv.x * wv.x + xv.y * wv.y + xv.z * wv.z + xv.w * wv.w;
#pragma unroll
  for (int off = 32; off > 0; off >>= 1) s += __shfl_down(s, off);
  if (lane == 0) out[n] = s + b[0];
}

// ---------------- host-side conv driver ----------------
static void run_conv(hipStream_t stream, const float* xin, const int* rp, const int* col,
                     const float* Wpre, const float* bpre, const float* Wpost,
                     const float* bpost, const float* Wlin, const float* blin,
                     float* hout, float* Abuf, float* Bbuf, float* agg, float* scal,
                     float* Wf, float* bf) {
  GemmSegs sx{};
  sx.ptr[0] = xin; sx.stride[0] = FD; sx.mode[0] = 0;
  // A = x@W1.T + bpre ; B = x@W2.T
  k_gemm<<<dim3(2, MT_NODES), 256, 0, stream>>>(sx, nullptr, Wpre, 2 * FD, 0, 0, bpre,
                                                Abuf, NN, FD, FD, 0);
  k_gemm<<<dim3(2, MT_NODES), 256, 0, stream>>>(sx, nullptr, Wpre, 2 * FD, FD, 0, nullptr,
                                                Bbuf, NN, FD, FD, 0);
  k_aggregate<<<NN, 256, 0, stream>>>(Abuf, Bbuf, rp, col, agg, scal);
  // Wf = Wlin @ Wpost  (M=256, Nout=4096, K=256, W read transposed)
  GemmSegs sl{};
  sl.ptr[0] = Wlin; sl.stride[0] = FD; sl.mode[0] = 0;
  k_gemm<<<dim3(32, 2), 256, 0, stream>>>(sl, nullptr, Wpost, 4096, 0, 1, nullptr, Wf,
                                          FD, 4096, FD, 0);
  k_bfuse<<<1, 256, 0, stream>>>(Wlin, bpost, blin, bf);
  // h = relu([x, agg, f1*agg, f2*agg] @ Wf.T + bf)
  GemmSegs sv{};
  sv.ptr[0] = xin; sv.stride[0] = FD; sv.mode[0] = 0;
  for (int pp = 0; pp < 5; ++pp) {
    sv.ptr[1 + pp] = agg + pp * FD;  sv.stride[1 + pp] = 1280;  sv.mode[1 + pp] = 0;
    sv.ptr[6 + pp] = agg + pp * FD;  sv.stride[6 + pp] = 1280;  sv.mode[6 + pp] = 1;
    sv.ptr[11 + pp] = agg + pp * FD; sv.stride[11 + pp] = 1280; sv.mode[11 + pp] = 2;
  }
  k_gemm<<<dim3(2, MT_NODES), 256, 0, stream>>>(sv, scal, Wf, 4096, 0, 0, bf, hout,
                                                NN, FD, 4096, 1);
}

extern "C" void kernel_launch(void* const* d_in, const int* in_sizes, int n_in,
                              void* d_out, int out_size, void* d_ws, size_t ws_size,
                              hipStream_t stream) {
  const float* x0      = (const float*)d_in[0];
  const int*   ei_in   = (const int*)d_in[1];
  const int*   ei_out  = (const int*)d_in[2];
  const float* Wpre_s  = (const float*)d_in[3];
  const float* bpre_s  = (const float*)d_in[4];
  const float* Wpost_s = (const float*)d_in[5];
  const float* bpost_s = (const float*)d_in[6];
  const float* Wlin_s  = (const float*)d_in[7];
  const float* blin_s  = (const float*)d_in[8];
  const float* Wpre_d  = (const float*)d_in[9];
  const float* bpre_d  = (const float*)d_in[10];
  const float* Wpost_d = (const float*)d_in[11];
  const float* bpost_d = (const float*)d_in[12];
  const float* Wlin_d  = (const float*)d_in[13];
  const float* blin_d  = (const float*)d_in[14];
  const float* Wcomb   = (const float*)d_in[15];
  const float* bcomb   = (const float*)d_in[16];
  const float* Wout    = (const float*)d_in[17];
  const float* bout    = (const float*)d_in[18];
  float* out = (float*)d_out;

  char* p = (char*)d_ws;
  auto alloc = [&](size_t b) {
    char* r = p;
    p += (b + 255) & ~(size_t)255;
    return r;
  };
  int* deg     = (int*)alloc((size_t)NN * 4);
  int* cur     = (int*)alloc((size_t)NN * 4);
  int* rp_in   = (int*)alloc((size_t)(NN + 1) * 4);
  int* col_in  = (int*)alloc((size_t)NE * 4);
  int* rp_out  = (int*)alloc((size_t)(NN + 1) * 4);
  int* col_out = (int*)alloc((size_t)NE * 4);
  float* Abuf  = (float*)alloc((size_t)NN * FD * 4);
  float* Bbuf  = (float*)alloc((size_t)NN * FD * 4);
  float* agg   = (float*)alloc((size_t)NN * 1280 * 4);
  float* scal  = (float*)alloc((size_t)NN * 2 * 4);
  float* Wf    = (float*)alloc((size_t)256 * 4096 * 4);
  float* bf    = (float*)alloc((size_t)256 * 4);
  float* h_in  = (float*)alloc((size_t)NN * FD * 4);
  float* h_out = (float*)alloc((size_t)NN * FD * 4);
  float* xb0   = (float*)alloc((size_t)NN * FD * 4);
  float* xb1   = (float*)alloc((size_t)NN * FD * 4);

  const int EB = (NE + 255) / 256;
  // CSR for in-edges (aggregate by dst = row 1; src = row 0)
  hipMemsetAsync(deg, 0, (size_t)NN * 4, stream);
  k_count<<<EB, 256, 0, stream>>>(ei_in + NE, deg, NE);
  k_scan<<<1, 1024, 0, stream>>>(deg, rp_in, NN);
  hipMemsetAsync(cur, 0, (size_t)NN * 4, stream);
  k_scatter<<<EB, 256, 0, stream>>>(ei_in, ei_in + NE, rp_in, cur, col_in, NE);
  // CSR for out-edges
  hipMemsetAsync(deg, 0, (size_t)NN * 4, stream);
  k_count<<<EB, 256, 0, stream>>>(ei_out + NE, deg, NE);
  k_scan<<<1, 1024, 0, stream>>>(deg, rp_out, NN);
  hipMemsetAsync(cur, 0, (size_t)NN * 4, stream);
  k_scatter<<<EB, 256, 0, stream>>>(ei_out, ei_out + NE, rp_out, cur, col_out, NE);

  const float* xin = x0;
  for (int l = 0; l < 2; ++l) {
    run_conv(stream, xin, rp_in, col_in,
             Wpre_s + (size_t)l * FD * 2 * FD, bpre_s + (size_t)l * FD,
             Wpost_s + (size_t)l * FD * 4096, bpost_s + (size_t)l * FD,
             Wlin_s + (size_t)l * FD * FD, blin_s + (size_t)l * FD,
             h_in, Abuf, Bbuf, agg, scal, Wf, bf);
    run_conv(stream, xin, rp_out, col_out,
             Wpre_d + (size_t)l * FD * 2 * FD, bpre_d + (size_t)l * FD,
             Wpost_d + (size_t)l * FD * 4096, bpost_d + (size_t)l * FD,
             Wlin_d + (size_t)l * FD * FD, blin_d + (size_t)l * FD,
             h_out, Abuf, Bbuf, agg, scal, Wf, bf);
    GemmSegs sc{};
    sc.ptr[0] = xin;   sc.stride[0] = FD; sc.mode[0] = 0;
    sc.ptr[1] = h_in;  sc.stride[1] = FD; sc.mode[1] = 0;
    sc.ptr[2] = h_out; sc.stride[2] = FD; sc.mode[2] = 0;
    float* xn = (l == 0) ? xb0 : xb1;
    k_gemm<<<dim3(2, MT_NODES), 256, 0, stream>>>(
        sc, nullptr, Wcomb + (size_t)l * FD * 768, 768, 0, 0, bcomb + (size_t)l * FD,
        xn, NN, FD, 768, 1);
    xin = xn;
  }
  k_wout<<<(NN + 3) / 4, 256, 0, stream>>>(xin, Wout, bout, out, NN);
}

// Round 3
// 937.585 us; speedup vs baseline: 5.0037x; 5.0037x over previous
//
#include <hip/hip_runtime.h>
#include <math.h>

#define NN 20000
#define NE 320000
#define FD 256
#define AVG_LOG_F 2.83321334f

typedef unsigned short u16;
typedef _Float16 h8_t __attribute__((ext_vector_type(8)));
typedef float f4_t __attribute__((ext_vector_type(4)));

__device__ __forceinline__ u16 f2h(float f) {
  _Float16 h = (_Float16)f;
  return __builtin_bit_cast(u16, h);
}
__device__ __forceinline__ float h2f(u16 u) {
  _Float16 h = __builtin_bit_cast(_Float16, u);
  return (float)h;
}
__device__ __forceinline__ void gld16(const void* g, void* l) {
  __builtin_amdgcn_global_load_lds(
      (const __attribute__((address_space(1))) void*)g,
      (__attribute__((address_space(3))) void*)l, 16, 0, 0);
}

// ---------------- CSR build ----------------
__global__ __launch_bounds__(256) void k_count(const int* __restrict__ dst,
                                               int* __restrict__ deg, int E) {
  int e = blockIdx.x * 256 + threadIdx.x;
  if (e < E) atomicAdd(&deg[dst[e]], 1);
}

__global__ __launch_bounds__(1024) void k_scan(const int* __restrict__ deg,
                                               int* __restrict__ rp, int N) {
  __shared__ int lds[1024];
  int t = threadIdx.x;
  int CH = (N + 1023) >> 10;
  int base = t * CH;
  int s = 0;
  for (int i = 0; i < CH; ++i) { int idx = base + i; if (idx < N) s += deg[idx]; }
  lds[t] = s;
  __syncthreads();
  for (int off = 1; off < 1024; off <<= 1) {
    int v = (t >= off) ? lds[t - off] : 0;
    __syncthreads();
    lds[t] += v;
    __syncthreads();
  }
  int run = (t == 0) ? 0 : lds[t - 1];
  for (int i = 0; i < CH; ++i) {
    int idx = base + i;
    if (idx < N) { rp[idx] = run; run += deg[idx]; }
  }
  if (t == 1023) rp[N] = run;
}

__global__ __launch_bounds__(256) void k_scatter(const int* __restrict__ src,
                                                 const int* __restrict__ dst,
                                                 const int* __restrict__ rp,
                                                 int* __restrict__ cur,
                                                 int* __restrict__ col, int E) {
  int e = blockIdx.x * 256 + threadIdx.x;
  if (e < E) {
    int d = dst[e];
    int p = atomicAdd(&cur[d], 1);
    col[rp[d] + p] = src[e];
  }
}

// ---------------- converts ----------------
__global__ __launch_bounds__(256) void k_cvt(const float* __restrict__ in,
                                             u16* __restrict__ out, int n4) {
  int i = blockIdx.x * 256 + threadIdx.x;
  if (i < n4) {
    float4 v = *(const float4*)(in + (size_t)i * 4);
    ushort4 o;
    o.x = f2h(v.x); o.y = f2h(v.y); o.z = f2h(v.z); o.w = f2h(v.w);
    *(ushort4*)(out + (size_t)i * 4) = o;
  }
}

// x0 -> xcat1[:,0:256] (ld 768)
__global__ __launch_bounds__(256) void k_cvtx(const float* __restrict__ x,
                                              u16* __restrict__ xc) {
  int i = blockIdx.x * 256 + threadIdx.x;  // over NN*64
  int row = i >> 6, c = (i & 63) * 4;
  float4 v = *(const float4*)(x + (size_t)row * 256 + c);
  ushort4 o;
  o.x = f2h(v.x); o.y = f2h(v.y); o.z = f2h(v.z); o.w = f2h(v.w);
  *(ushort4*)(xc + (size_t)row * 768 + c) = o;
}

// transpose-convert Wpost [256,4096] f32 -> [4096,256] fp16
__global__ __launch_bounds__(256) void k_tc(const float* __restrict__ in,
                                            u16* __restrict__ out) {
  __shared__ float tile[32][33];
  int bx = blockIdx.x;  // j tile (4096 dim)
  int by = blockIdx.y;  // o tile (256 dim)
  int r = threadIdx.x >> 5, c = threadIdx.x & 31;
#pragma unroll
  for (int it = 0; it < 4; ++it)
    tile[r + it * 8][c] = in[(size_t)(by * 32 + r + it * 8) * 4096 + bx * 32 + c];
  __syncthreads();
#pragma unroll
  for (int it = 0; it < 4; ++it)
    out[(size_t)(bx * 32 + r + it * 8) * 256 + by * 32 + c] = f2h(tile[c][r + it * 8]);
}

// ---------------- MFMA fp16 GEMM: C[m,n] = sum_k A[m,k]*Brow[n,k] ----------------
// BM=64, BN=256, BK=64, 512 threads (8 waves, 2x4 of 32x64 tiles)
__global__ __launch_bounds__(512) void k_mgemm(
    const u16* __restrict__ A, int lda,
    const u16* __restrict__ B, const u16* __restrict__ B2, int ldb, int nsplit,
    const float* __restrict__ bias, const float* __restrict__ bias2,
    float* __restrict__ oF, int ldoF, int ncutF,
    u16* __restrict__ oH, int ldoH,
    int M, int K, int relu) {
  __shared__ u16 As[64 * 64];
  __shared__ u16 Bs[256 * 64];
  const int t = threadIdx.x;
  const int m0 = blockIdx.y * 64;
  const int n0 = blockIdx.x * 256;
  const int l = t & 63;
  const int w = t >> 6;
  const int wm = w >> 2, wn = w & 3;
  const int lo = l & 15, hi = l >> 4;

  f4_t acc[2][4];
#pragma unroll
  for (int i = 0; i < 2; ++i)
#pragma unroll
    for (int j = 0; j < 4; ++j) acc[i][j] = (f4_t)0.f;

  // A staging: 512 chunks of 16B, 1 per thread; pre-swizzled global source
  int ra = t >> 3, pa = t & 7;
  int la = pa ^ (ra & 7);
  int rra = m0 + ra;
  if (rra > M - 1) rra = M - 1;
  const u16* gA = A + (size_t)rra * lda + la * 8;
  u16* lA = &As[t * 8];

  // B staging: 2048 chunks, 4 per thread
  const u16* gB[4];
  u16* lB[4];
#pragma unroll
  for (int i = 0; i < 4; ++i) {
    int q = i * 512 + t;
    int r = q >> 3, p = q & 7;
    int lc = p ^ (r & 7);
    int n = n0 + r;
    const u16* bp = (n < nsplit) ? (B + (size_t)n * ldb)
                                 : (B2 + (size_t)(n - nsplit) * ldb);
    gB[i] = bp + lc * 8;
    lB[i] = &Bs[q * 8];
  }

  for (int k0 = 0; k0 < K; k0 += 64) {
    gld16(gA + k0, lA);
#pragma unroll
    for (int i = 0; i < 4; ++i) gld16(gB[i] + k0, lB[i]);
    __syncthreads();
#pragma unroll
    for (int ks = 0; ks < 2; ++ks) {
      h8_t af[2], bf[4];
#pragma unroll
      for (int mi = 0; mi < 2; ++mi) {
        int row = wm * 32 + mi * 16 + lo;
        int c = (ks * 4 + hi) ^ (row & 7);
        af[mi] = *(const h8_t*)&As[row * 64 + c * 8];
      }
#pragma unroll
      for (int ni = 0; ni < 4; ++ni) {
        int row = wn * 64 + ni * 16 + lo;
        int c = (ks * 4 + hi) ^ (row & 7);
        bf[ni] = *(const h8_t*)&Bs[row * 64 + c * 8];
      }
#pragma unroll
      for (int mi = 0; mi < 2; ++mi)
#pragma unroll
        for (int ni = 0; ni < 4; ++ni)
          acc[mi][ni] = __builtin_amdgcn_mfma_f32_16x16x32_f16(
              af[mi], bf[ni], acc[mi][ni], 0, 0, 0);
    }
    __syncthreads();
  }

  float bv[4];
#pragma unroll
  for (int ni = 0; ni < 4; ++ni) {
    int n = n0 + wn * 64 + ni * 16 + lo;
    bv[ni] = (n < nsplit) ? (bias ? bias[n] : 0.f)
                          : (bias2 ? bias2[n - nsplit] : 0.f);
  }
#pragma unroll
  for (int mi = 0; mi < 2; ++mi) {
#pragma unroll
    for (int r = 0; r < 4; ++r) {
      int m = m0 + wm * 32 + mi * 16 + hi * 4 + r;
      if (m < M) {
#pragma unroll
        for (int ni = 0; ni < 4; ++ni) {
          int n = n0 + wn * 64 + ni * 16 + lo;
          float v = acc[mi][ni][r] + bv[ni];
          if (relu && v < 0.f) v = 0.f;
          if (n < ncutF) {
            oF[(size_t)m * ldoF + n] = v;
          } else {
            oH[(size_t)m * ldoH + (n - ncutF)] = f2h(v);
          }
        }
      }
    }
  }
}

// ---------------- post GEMM with virtual A = [x | agg*f0 | agg*f1 | agg*f2] ----------------
// h[m,n] = relu( sum_{k<4096} V[m,k]*Wf[n,k] + bf[n] ), n in [0,256)
// V[m,k]: k<256 -> xc[m*768+k]; else q=k-256, g=q/1280, r=q%1280:
//         agg5[m*1280+r] * scal3[m*4+g]   (scal3[m*4+0]==1)
__global__ __launch_bounds__(512) void k_pgemm(
    const u16* __restrict__ xc, const u16* __restrict__ agg5,
    const float* __restrict__ scal3, const u16* __restrict__ Wf,
    const float* __restrict__ bf, u16* __restrict__ oH, int M) {
  __shared__ u16 As[64 * 64];
  __shared__ u16 Bs[256 * 64];
  const int t = threadIdx.x;
  const int m0 = blockIdx.x * 64;
  const int l = t & 63;
  const int w = t >> 6;
  const int wm = w >> 2, wn = w & 3;
  const int lo = l & 15, hi = l >> 4;

  f4_t acc[2][4];
#pragma unroll
  for (int i = 0; i < 2; ++i)
#pragma unroll
    for (int j = 0; j < 4; ++j) acc[i][j] = (f4_t)0.f;

  // A reg-staging: thread t -> row ra, k-chunk pa (8 u16); swizzled LDS write
  const int ra = t >> 3, pa = t & 7;
  int m = m0 + ra;
  if (m > M - 1) m = M - 1;
  u16* ldA = &As[ra * 64 + (pa ^ (ra & 7)) * 8];
  const u16* xrow = xc + (size_t)m * 768;
  const u16* arow = agg5 + (size_t)m * 1280;
  const float* srow = scal3 + (size_t)m * 4;

  // B staging: direct global->LDS, pre-swizzled source (n0 == 0 always)
  const u16* gB[4];
  u16* lB[4];
#pragma unroll
  for (int i = 0; i < 4; ++i) {
    int q = i * 512 + t;
    int r = q >> 3, p = q & 7;
    int lc = p ^ (r & 7);
    gB[i] = Wf + (size_t)r * 4096 + lc * 8;
    lB[i] = &Bs[q * 8];
  }

  for (int k0 = 0; k0 < 4096; k0 += 64) {
#pragma unroll
    for (int i = 0; i < 4; ++i) gld16(gB[i] + k0, lB[i]);
    int k = k0 + pa * 8;
    h8_t v;
    if (k < 256) {
      v = *(const h8_t*)(xrow + k);
    } else {
      int q = k - 256;
      int g = q / 1280;
      int r2 = q - g * 1280;
      v = *(const h8_t*)(arow + r2);
      v = v * (_Float16)srow[g];
    }
    *(h8_t*)ldA = v;
    __syncthreads();
#pragma unroll
    for (int ks = 0; ks < 2; ++ks) {
      h8_t af[2], bfr[4];
#pragma unroll
      for (int mi = 0; mi < 2; ++mi) {
        int row = wm * 32 + mi * 16 + lo;
        int c = (ks * 4 + hi) ^ (row & 7);
        af[mi] = *(const h8_t*)&As[row * 64 + c * 8];
      }
#pragma unroll
      for (int ni = 0; ni < 4; ++ni) {
        int row = wn * 64 + ni * 16 + lo;
        int c = (ks * 4 + hi) ^ (row & 7);
        bfr[ni] = *(const h8_t*)&Bs[row * 64 + c * 8];
      }
#pragma unroll
      for (int mi = 0; mi < 2; ++mi)
#pragma unroll
        for (int ni = 0; ni < 4; ++ni)
          acc[mi][ni] = __builtin_amdgcn_mfma_f32_16x16x32_f16(
              af[mi], bfr[ni], acc[mi][ni], 0, 0, 0);
    }
    __syncthreads();
  }

  float bv[4];
#pragma unroll
  for (int ni = 0; ni < 4; ++ni) bv[ni] = bf[wn * 64 + ni * 16 + lo];
#pragma unroll
  for (int mi = 0; mi < 2; ++mi) {
#pragma unroll
    for (int r = 0; r < 4; ++r) {
      int mr = m0 + wm * 32 + mi * 16 + hi * 4 + r;
      if (mr < M) {
#pragma unroll
        for (int ni = 0; ni < 4; ++ni) {
          int n = wn * 64 + ni * 16 + lo;
          float vv = acc[mi][ni][r] + bv[ni];
          if (vv < 0.f) vv = 0.f;
          oH[(size_t)mr * 768 + n] = f2h(vv);
        }
      }
    }
  }
}

// ---------------- aggregation: wave per node, 4 features/lane ----------------
__global__ __launch_bounds__(256) void k_aggregate(
    const float* __restrict__ A, const u16* __restrict__ Bh,
    const int* __restrict__ rp, const int* __restrict__ col,
    u16* __restrict__ agg5, float* __restrict__ scal3) {
  int w = threadIdx.x >> 6, l = threadIdx.x & 63;
  int n = blockIdx.x * 4 + w;
  int beg = rp[n], end = rp[n + 1];
  int deg = end - beg;
  float sb[4] = {0.f, 0.f, 0.f, 0.f}, qb[4] = {0.f, 0.f, 0.f, 0.f};
  float mnb[4], mxb[4];
#pragma unroll
  for (int j = 0; j < 4; ++j) { mnb[j] = 3.402823466e38f; mxb[j] = -3.402823466e38f; }
  for (int i = beg; i < end; ++i) {
    int s = col[i];
    ushort4 bv = *(const ushort4*)(Bh + (size_t)s * FD + l * 4);
    float b[4] = {h2f(bv.x), h2f(bv.y), h2f(bv.z), h2f(bv.w)};
#pragma unroll
    for (int j = 0; j < 4; ++j) {
      sb[j] += b[j];
      qb[j] = fmaf(b[j], b[j], qb[j]);
      mnb[j] = fminf(mnb[j], b[j]);
      mxb[j] = fmaxf(mxb[j], b[j]);
    }
  }
  float4 c4 = *(const float4*)(A + (size_t)n * FD + l * 4);
  float cc[4] = {c4.x, c4.y, c4.z, c4.w};
  float degf = (float)deg;
  float degc = degf > 1.f ? degf : 1.f;
  float inv = 1.f / degc;
  float outv[5][4];
#pragma unroll
  for (int j = 0; j < 4; ++j) {
    float c = cc[j];
    float s_m = fmaf(degf, c, sb[j]);
    float mean = s_m * inv;
    float mean2 = fmaf(degf * c, c, fmaf(2.f * c, sb[j], qb[j])) * inv;
    float var = mean2 - mean * mean;
    if (var < 0.f) var = 0.f;
    float sd = sqrtf(var + 1e-5f);
    outv[0][j] = mean;
    outv[1][j] = s_m;
    outv[2][j] = sd;
    outv[3][j] = deg > 0 ? c + mnb[j] : 0.f;
    outv[4][j] = deg > 0 ? c + mxb[j] : 0.f;
  }
  u16* base = agg5 + (size_t)n * 1280 + l * 4;
#pragma unroll
  for (int a = 0; a < 5; ++a) {
    ushort4 o;
    o.x = f2h(outv[a][0]);
    o.y = f2h(outv[a][1]);
    o.z = f2h(outv[a][2]);
    o.w = f2h(outv[a][3]);
    *(ushort4*)(base + a * 256) = o;
  }
  if (l == 0) {
    float logd = logf(degc + 1.f);
    scal3[(size_t)n * 4 + 0] = 1.f;
    scal3[(size_t)n * 4 + 1] = logd / AVG_LOG_F;
    scal3[(size_t)n * 4 + 2] = AVG_LOG_F / logd;
    scal3[(size_t)n * 4 + 3] = 0.f;
  }
}

// bf = Wlin @ bpost + blin (fp32)
__global__ __launch_bounds__(256) void k_bfuse(const float* __restrict__ Wlin,
                                               const float* __restrict__ bpost,
                                               const float* __restrict__ blin,
                                               float* __restrict__ bf) {
  __shared__ float bp[256];
  int t = threadIdx.x;
  bp[t] = bpost[t];
  __syncthreads();
  float s = blin[t];
  for (int k = 0; k < 256; ++k) s = fmaf(Wlin[t * 256 + k], bp[k], s);
  bf[t] = s;
}

__global__ __launch_bounds__(256) void k_wout(const u16* __restrict__ x,
                                              const float* __restrict__ w,
                                              const float* __restrict__ b,
                                              float* __restrict__ out, int N) {
  int wid = threadIdx.x >> 6, lane = threadIdx.x & 63;
  int n = blockIdx.x * 4 + wid;
  if (n >= N) return;
  ushort4 xv = *(const ushort4*)(x + (size_t)n * FD + lane * 4);
  const float4 wv = *(const float4*)(w + lane * 4);
  float s = h2f(xv.x) * wv.x + h2f(xv.y) * wv.y + h2f(xv.z) * wv.z + h2f(xv.w) * wv.w;
#pragma unroll
  for (int off = 32; off > 0; off >>= 1) s += __shfl_down(s, off);
  if (lane == 0) out[n] = s + b[0];
}

extern "C" void kernel_launch(void* const* d_in, const int* in_sizes, int n_in,
                              void* d_out, int out_size, void* d_ws, size_t ws_size,
                              hipStream_t stream) {
  const float* x0      = (const float*)d_in[0];
  const int*   ei_in   = (const int*)d_in[1];
  const int*   ei_out  = (const int*)d_in[2];
  const float* Wpre_s  = (const float*)d_in[3];
  const float* bpre_s  = (const float*)d_in[4];
  const float* Wpost_s = (const float*)d_in[5];
  const float* bpost_s = (const float*)d_in[6];
  const float* Wlin_s  = (const float*)d_in[7];
  const float* blin_s  = (const float*)d_in[8];
  const float* Wpre_d  = (const float*)d_in[9];
  const float* bpre_d  = (const float*)d_in[10];
  const float* Wpost_d = (const float*)d_in[11];
  const float* bpost_d = (const float*)d_in[12];
  const float* Wlin_d  = (const float*)d_in[13];
  const float* blin_d  = (const float*)d_in[14];
  const float* Wcomb   = (const float*)d_in[15];
  const float* bcomb   = (const float*)d_in[16];
  const float* Wout    = (const float*)d_in[17];
  const float* bout    = (const float*)d_in[18];
  float* out = (float*)d_out;

  char* p = (char*)d_ws;
  auto alloc = [&](size_t b) {
    char* r = p;
    p += (b + 255) & ~(size_t)255;
    return r;
  };
  int* deg      = (int*)alloc((size_t)NN * 4);
  int* cur      = (int*)alloc((size_t)NN * 4);
  int* rp_in    = (int*)alloc((size_t)(NN + 1) * 4);
  int* col_in   = (int*)alloc((size_t)NE * 4);
  int* rp_out   = (int*)alloc((size_t)(NN + 1) * 4);
  int* col_out  = (int*)alloc((size_t)NE * 4);
  float* Abuf   = (float*)alloc((size_t)NN * FD * 4);
  u16* Bbuf     = (u16*)alloc((size_t)NN * FD * 2);
  u16* agg5     = (u16*)alloc((size_t)NN * 1280 * 2);
  float* scal3  = (float*)alloc((size_t)NN * 4 * 4);
  u16* xcat1    = (u16*)alloc((size_t)NN * 768 * 2);
  u16* xcat2    = (u16*)alloc((size_t)NN * 768 * 2);
  u16* xfin     = (u16*)alloc((size_t)NN * FD * 2);
  u16* Wpre_sb  = (u16*)alloc((size_t)2 * 256 * 512 * 2);
  u16* Wpre_db  = (u16*)alloc((size_t)2 * 256 * 512 * 2);
  u16* Wlin_sb  = (u16*)alloc((size_t)2 * 256 * 256 * 2);
  u16* Wlin_db  = (u16*)alloc((size_t)2 * 256 * 256 * 2);
  u16* Wcomb_b  = (u16*)alloc((size_t)2 * 256 * 768 * 2);
  u16* WpostT   = (u16*)alloc((size_t)4096 * 256 * 2);
  u16* Wf       = (u16*)alloc((size_t)256 * 4096 * 2);
  float* bfv    = (float*)alloc((size_t)256 * 4);

  const int EB = (NE + 255) / 256;
  const int BIG = 1 << 30;

  // weight converts
  k_cvt<<<256, 256, 0, stream>>>(Wpre_s, Wpre_sb, 65536);
  k_cvt<<<256, 256, 0, stream>>>(Wpre_d, Wpre_db, 65536);
  k_cvt<<<128, 256, 0, stream>>>(Wlin_s, Wlin_sb, 32768);
  k_cvt<<<128, 256, 0, stream>>>(Wlin_d, Wlin_db, 32768);
  k_cvt<<<384, 256, 0, stream>>>(Wcomb, Wcomb_b, 98304);
  k_cvtx<<<5000, 256, 0, stream>>>(x0, xcat1);

  // CSR builds
  hipMemsetAsync(deg, 0, (size_t)NN * 4, stream);
  k_count<<<EB, 256, 0, stream>>>(ei_in + NE, deg, NE);
  k_scan<<<1, 1024, 0, stream>>>(deg, rp_in, NN);
  hipMemsetAsync(cur, 0, (size_t)NN * 4, stream);
  k_scatter<<<EB, 256, 0, stream>>>(ei_in, ei_in + NE, rp_in, cur, col_in, NE);
  hipMemsetAsync(deg, 0, (size_t)NN * 4, stream);
  k_count<<<EB, 256, 0, stream>>>(ei_out + NE, deg, NE);
  k_scan<<<1, 1024, 0, stream>>>(deg, rp_out, NN);
  hipMemsetAsync(cur, 0, (size_t)NN * 4, stream);
  k_scatter<<<EB, 256, 0, stream>>>(ei_out, ei_out + NE, rp_out, cur, col_out, NE);

  u16* xcats[2] = {xcat1, xcat2};
  for (int lyr = 0; lyr < 2; ++lyr) {
    u16* xc = xcats[lyr];
    for (int c = 0; c < 2; ++c) {  // c=0: in-edges ("s" params); c=1: out-edges ("d")
      const float* bpre  = (c == 0) ? bpre_s : bpre_d;
      const float* Wpost = (c == 0) ? Wpost_s : Wpost_d;
      const float* bpost = (c == 0) ? bpost_s : bpost_d;
      const float* Wlin  = (c == 0) ? Wlin_s : Wlin_d;
      const float* blin  = (c == 0) ? blin_s : blin_d;
      u16* Wpre_b = (c == 0) ? Wpre_sb : Wpre_db;
      u16* Wlin_b = (c == 0) ? Wlin_sb : Wlin_db;
      const int* rp  = (c == 0) ? rp_in : rp_out;
      const int* col = (c == 0) ? col_in : col_out;

      // pre: [A | B] = x @ [W1 | W2]^T, N=512 split at 256
      k_mgemm<<<dim3(2, 313), 512, 0, stream>>>(
          xc, 768,
          Wpre_b + (size_t)lyr * 131072, Wpre_b + (size_t)lyr * 131072 + 256, 512, 256,
          bpre + (size_t)lyr * 256, nullptr,
          Abuf, 256, 256,
          Bbuf, 256,
          NN, 256, 0);
      k_aggregate<<<5000, 256, 0, stream>>>(Abuf, Bbuf, rp, col, agg5, scal3);
      k_tc<<<dim3(128, 8), 256, 0, stream>>>(Wpost + (size_t)lyr * 256 * 4096, WpostT);
      // Wf = Wlin @ Wpost  (uses transposed WpostT as B)
      k_mgemm<<<dim3(16, 4), 512, 0, stream>>>(
          Wlin_b + (size_t)lyr * 65536, 256,
          WpostT, WpostT, 256, BIG,
          nullptr, nullptr,
          nullptr, 0, 0,
          Wf, 4096,
          256, 256, 0);
      k_bfuse<<<1, 256, 0, stream>>>(Wlin + (size_t)lyr * 65536,
                                     bpost + (size_t)lyr * 256,
                                     blin + (size_t)lyr * 256, bfv);
      // h = relu(V @ Wf^T + bf) -> xcat[:, 256 or 512], V virtual from xc/agg5/scal3
      k_pgemm<<<dim3(313), 512, 0, stream>>>(
          xc, agg5, scal3, Wf, bfv, xc + 256 + c * 256, NN);
    }
    // comb: x_next = relu([x, h_in, h_out] @ Wcomb^T + bcomb)
    if (lyr == 0) {
      k_mgemm<<<dim3(1, 313), 512, 0, stream>>>(
          xc, 768,
          Wcomb_b, Wcomb_b, 768, BIG,
          bcomb, nullptr,
          nullptr, 0, 0,
          xcat2, 768,
          NN, 768, 1);
    } else {
      k_mgemm<<<dim3(1, 313), 512, 0, stream>>>(
          xc, 768,
          Wcomb_b + 196608, Wcomb_b + 196608, 768, BIG,
          bcomb + 256, nullptr,
          nullptr, 0, 0,
          xfin, 256,
          NN, 768, 1);
    }
  }
  k_wout<<<5000, 256, 0, stream>>>(xfin, Wout, bout, out, NN);
}

// Round 5
// 852.370 us; speedup vs baseline: 5.5039x; 1.1000x over previous
//
#include <hip/hip_runtime.h>
#include <math.h>

#define NN 20000
#define NE 320000
#define AVG_LOG_F 2.83321334f

typedef unsigned short u16;
typedef _Float16 h8_t __attribute__((ext_vector_type(8)));
typedef float f4_t __attribute__((ext_vector_type(4)));

__device__ __forceinline__ u16 f2h(float f) {
  _Float16 h = (_Float16)f;
  return __builtin_bit_cast(u16, h);
}
__device__ __forceinline__ void gld16(const void* g, void* l) {
  __builtin_amdgcn_global_load_lds(
      (const __attribute__((address_space(1))) void*)g,
      (__attribute__((address_space(3))) void*)l, 16, 0, 0);
}

// ---------------- CSR build (both channels in one pass) ----------------
__global__ __launch_bounds__(256) void k_count2(const int* __restrict__ ein,
                                                const int* __restrict__ eout,
                                                int* __restrict__ deg2, int E) {
  int e = blockIdx.x * 256 + threadIdx.x;
  int ch = blockIdx.y;
  const int* dst = (ch ? eout : ein) + E;
  if (e < E) atomicAdd(&deg2[ch * NN + dst[e]], 1);
}

__global__ __launch_bounds__(1024) void k_scan(const int* __restrict__ deg,
                                               int* __restrict__ rp, int N) {
  __shared__ int lds[1024];
  int t = threadIdx.x;
  int CH = (N + 1023) >> 10;
  int base = t * CH;
  int s = 0;
  for (int i = 0; i < CH; ++i) { int idx = base + i; if (idx < N) s += deg[idx]; }
  lds[t] = s;
  __syncthreads();
  for (int off = 1; off < 1024; off <<= 1) {
    int v = (t >= off) ? lds[t - off] : 0;
    __syncthreads();
    lds[t] += v;
    __syncthreads();
  }
  int run = (t == 0) ? 0 : lds[t - 1];
  for (int i = 0; i < CH; ++i) {
    int idx = base + i;
    if (idx < N) { rp[idx] = run; run += deg[idx]; }
  }
  if (t == 1023) rp[N] = run;
}

__global__ __launch_bounds__(256) void k_scatter2(const int* __restrict__ ein,
                                                  const int* __restrict__ eout,
                                                  const int* __restrict__ rp2,
                                                  int* __restrict__ cur2,
                                                  int* __restrict__ col2, int E) {
  int e = blockIdx.x * 256 + threadIdx.x;
  int ch = blockIdx.y;
  const int* src = (ch ? eout : ein);
  const int* dst = src + E;
  if (e < E) {
    int d = dst[e];
    int p = atomicAdd(&cur2[ch * NN + d], 1);
    col2[rp2[ch * NN + d] + p] = src[e];
  }
}

// ---------------- converts ----------------
// merged weight convert: Wpre_s, Wpre_d, Wlin_s->lincat(z=2lyr), Wlin_d->lincat(z=2lyr+1), Wcomb
__global__ __launch_bounds__(256) void k_cvtw(
    const float* __restrict__ Wpre_s, const float* __restrict__ Wpre_d,
    const float* __restrict__ Wlin_s, const float* __restrict__ Wlin_d,
    const float* __restrict__ Wcomb,
    u16* __restrict__ preS, u16* __restrict__ preD,
    u16* __restrict__ lincat, u16* __restrict__ combB) {
  int i = blockIdx.x * 256 + threadIdx.x;  // float4 index
  const float* src;
  u16* dst;
  int so, dofs;
  if (i < 65536)       { src = Wpre_s; dst = preS;  so = i;          dofs = so; }
  else if (i < 131072) { src = Wpre_d; dst = preD;  so = i - 65536;  dofs = so; }
  else if (i < 163840) { int j = i - 131072; int lyr = j >> 14;
                         src = Wlin_s; dst = lincat; so = j; dofs = j + lyr * 16384; }
  else if (i < 196608) { int j = i - 163840; int lyr = j >> 14;
                         src = Wlin_d; dst = lincat; so = j; dofs = j + (lyr + 1) * 16384; }
  else if (i < 294912) { src = Wcomb; dst = combB; so = i - 196608; dofs = so; }
  else return;
  float4 v = *(const float4*)(src + (size_t)so * 4);
  ushort4 o;
  o.x = f2h(v.x); o.y = f2h(v.y); o.z = f2h(v.z); o.w = f2h(v.w);
  *(ushort4*)(dst + (size_t)dofs * 4) = o;
}

// x0 -> xcat1[:,0:256] (ld 768)
__global__ __launch_bounds__(256) void k_cvtx(const float* __restrict__ x,
                                              u16* __restrict__ xc) {
  int i = blockIdx.x * 256 + threadIdx.x;  // over NN*64
  int row = i >> 6, c = (i & 63) * 4;
  float4 v = *(const float4*)(x + (size_t)row * 256 + c);
  ushort4 o;
  o.x = f2h(v.x); o.y = f2h(v.y); o.z = f2h(v.z); o.w = f2h(v.w);
  *(ushort4*)(xc + (size_t)row * 768 + c) = o;
}

// transpose-convert Wpost [256,4096] f32 -> [4096,256] fp16, all 4 (lyr,ch)
__global__ __launch_bounds__(256) void k_tc4(const float* __restrict__ Ws,
                                             const float* __restrict__ Wd,
                                             u16* __restrict__ outT) {
  __shared__ float tile[32][33];
  int z = blockIdx.z;
  const float* in = ((z & 1) ? Wd : Ws) + (size_t)(z >> 1) * 256 * 4096;
  u16* out = outT + (size_t)z * (4096 * 256);
  int bx = blockIdx.x, by = blockIdx.y;
  int r = threadIdx.x >> 5, c = threadIdx.x & 31;
#pragma unroll
  for (int it = 0; it < 4; ++it)
    tile[r + it * 8][c] = in[(size_t)(by * 32 + r + it * 8) * 4096 + bx * 32 + c];
  __syncthreads();
#pragma unroll
  for (int it = 0; it < 4; ++it)
    out[(size_t)(bx * 32 + r + it * 8) * 256 + by * 32 + c] = f2h(tile[c][r + it * 8]);
}

// ---------------- MFMA fp16 GEMM, double-buffered ----------------
// C[m,n] = sum_k A[m,k]*Brow[n,k] (+bias) (opt relu); out fp16.
// BM=64, BN=256, BK=64, 512 threads. blockIdx.z strides A/B/out for batched use.
__global__ __launch_bounds__(512) void k_mgemm(
    const u16* __restrict__ A, int lda,
    const u16* __restrict__ B, const u16* __restrict__ B2, int ldb, int nsplit,
    const float* __restrict__ bias,
    u16* __restrict__ oH, int ldoH,
    int M, int K, int relu, int zA, int zB, int zO) {
  __shared__ u16 As[2][64 * 64];
  __shared__ u16 Bs[2][256 * 64];
  const int t = threadIdx.x;
  const int z = blockIdx.z;
  A += (size_t)z * zA;
  B += (size_t)z * zB;
  B2 += (size_t)z * zB;
  oH += (size_t)z * zO;
  const int m0 = blockIdx.y * 64;
  const int n0 = blockIdx.x * 256;
  const int l = t & 63, w = t >> 6;
  const int wm = w >> 2, wn = w & 3;
  const int lo = l & 15, hi = l >> 4;

  f4_t acc[2][4];
#pragma unroll
  for (int i = 0; i < 2; ++i)
#pragma unroll
    for (int j = 0; j < 4; ++j) acc[i][j] = (f4_t)0.f;

  const int ra = t >> 3, pa = t & 7;
  const int la = pa ^ (ra & 7);
  int rra = m0 + ra;
  if (rra > M - 1) rra = M - 1;
  const u16* gA = A + (size_t)rra * lda + la * 8;

  const u16* gB[4];
  int lBo[4];
#pragma unroll
  for (int i = 0; i < 4; ++i) {
    int q = i * 512 + t;
    int r = q >> 3, p2 = q & 7;
    int lc = p2 ^ (r & 7);
    int n = n0 + r;
    const u16* bp = (n < nsplit) ? (B + (size_t)n * ldb) : (B2 + (size_t)(n - nsplit) * ldb);
    gB[i] = bp + lc * 8;
    lBo[i] = q * 8;
  }

  // prologue: stage tile 0 into buf 0
  gld16(gA, &As[0][t * 8]);
#pragma unroll
  for (int i = 0; i < 4; ++i) gld16(gB[i], &Bs[0][lBo[i]]);
  __syncthreads();

  const int nt = K >> 6;
  for (int tt = 0; tt < nt; ++tt) {
    const int cur = tt & 1;
    if (tt + 1 < nt) {  // stage next tile; loads overlap MFMA below
      const int ko = (tt + 1) << 6;
      gld16(gA + ko, &As[cur ^ 1][t * 8]);
#pragma unroll
      for (int i = 0; i < 4; ++i) gld16(gB[i] + ko, &Bs[cur ^ 1][lBo[i]]);
    }
#pragma unroll
    for (int ks = 0; ks < 2; ++ks) {
      h8_t af[2], bfr[4];
#pragma unroll
      for (int mi = 0; mi < 2; ++mi) {
        int row = wm * 32 + mi * 16 + lo;
        int c = (ks * 4 + hi) ^ (row & 7);
        af[mi] = *(const h8_t*)&As[cur][row * 64 + c * 8];
      }
#pragma unroll
      for (int ni = 0; ni < 4; ++ni) {
        int row = wn * 64 + ni * 16 + lo;
        int c = (ks * 4 + hi) ^ (row & 7);
        bfr[ni] = *(const h8_t*)&Bs[cur][row * 64 + c * 8];
      }
#pragma unroll
      for (int mi = 0; mi < 2; ++mi)
#pragma unroll
        for (int ni = 0; ni < 4; ++ni)
          acc[mi][ni] = __builtin_amdgcn_mfma_f32_16x16x32_f16(
              af[mi], bfr[ni], acc[mi][ni], 0, 0, 0);
    }
    __syncthreads();  // drains next-tile loads + gates buffer reuse
  }

  float bv[4];
#pragma unroll
  for (int ni = 0; ni < 4; ++ni) {
    int n = n0 + wn * 64 + ni * 16 + lo;
    bv[ni] = (n < nsplit) ? (bias ? bias[n] : 0.f) : 0.f;
  }
#pragma unroll
  for (int mi = 0; mi < 2; ++mi) {
#pragma unroll
    for (int r = 0; r < 4; ++r) {
      int m = m0 + wm * 32 + mi * 16 + hi * 4 + r;
      if (m < M) {
#pragma unroll
        for (int ni = 0; ni < 4; ++ni) {
          int n = n0 + wn * 64 + ni * 16 + lo;
          float v = acc[mi][ni][r] + bv[ni];
          if (relu && v < 0.f) v = 0.f;
          oH[(size_t)m * ldoH + n] = f2h(v);
        }
      }
    }
  }
}

// ---------------- post GEMM, channel-merged, double-buffered ----------------
// virtual A = [x | agg | agg*s1 | agg*s2]; B = Wf (per channel); out fp16 into xc cols.
__global__ __launch_bounds__(512) void k_pgemm(
    const u16* __restrict__ xc, const u16* __restrict__ agg5c,
    const float* __restrict__ scal3c, const u16* __restrict__ Wfl,
    const float* __restrict__ bfl, u16* __restrict__ oHb, int M) {
  __shared__ u16 As[2][64 * 64];
  __shared__ u16 Bs[2][256 * 64];
  const int t = threadIdx.x;
  const int ch = blockIdx.y;
  const u16* agg5 = agg5c + (size_t)ch * NN * 1280;
  const float* scal3 = scal3c + (size_t)ch * NN * 4;
  const u16* Wf = Wfl + (size_t)ch * (256 * 4096);
  const float* bf = bfl + ch * 256;
  u16* oH = oHb + 256 + ch * 256;  // ldoH = 768
  const int m0 = blockIdx.x * 64;
  const int l = t & 63, w = t >> 6;
  const int wm = w >> 2, wn = w & 3;
  const int lo = l & 15, hi = l >> 4;

  f4_t acc[2][4];
#pragma unroll
  for (int i = 0; i < 2; ++i)
#pragma unroll
    for (int j = 0; j < 4; ++j) acc[i][j] = (f4_t)0.f;

  // A reg-staging: thread -> row ra, k-chunk pa (8 fp16); swizzled LDS slot
  const int ra = t >> 3, pa = t & 7;
  int m = m0 + ra;
  if (m > M - 1) m = M - 1;
  const u16* xrow = xc + (size_t)m * 768;
  const u16* arow = agg5 + (size_t)m * 1280;
  const float s1 = scal3[(size_t)m * 4 + 1];
  const float s2 = scal3[(size_t)m * 4 + 2];
  const int aslot = ra * 64 + (pa ^ (ra & 7)) * 8;

  // B: direct global->LDS, pre-swizzled source (n0==0)
  const u16* gB[4];
  int lBo[4];
#pragma unroll
  for (int i = 0; i < 4; ++i) {
    int q = i * 512 + t;
    int r = q >> 3, p2 = q & 7;
    int lc = p2 ^ (r & 7);
    gB[i] = Wf + (size_t)r * 4096 + lc * 8;
    lBo[i] = q * 8;
  }

  // prologue: tile 0 (k<256 -> x segment always)
  {
    h8_t va = *(const h8_t*)(xrow + pa * 8);
#pragma unroll
    for (int i = 0; i < 4; ++i) gld16(gB[i], &Bs[0][lBo[i]]);
    *(h8_t*)&As[0][aslot] = va;
  }
  __syncthreads();

  for (int tt = 0; tt < 64; ++tt) {
    const int cur = tt & 1;
    h8_t va2 = (h8_t)(_Float16)0.f;
    float fac = 1.f;
    if (tt < 63) {
      int k = ((tt + 1) << 6) + pa * 8;
      const u16* ap;
      if (k < 256) {
        ap = xrow + k;
      } else {
        int q = k - 256;
        int r2 = q < 1280 ? q : (q < 2560 ? q - 1280 : q - 2560);
        fac = q < 1280 ? 1.f : (q < 2560 ? s1 : s2);
        ap = arow + r2;
      }
      va2 = *(const h8_t*)ap;
#pragma unroll
      for (int i = 0; i < 4; ++i) gld16(gB[i] + ((tt + 1) << 6), &Bs[cur ^ 1][lBo[i]]);
    }
#pragma unroll
    for (int ks = 0; ks < 2; ++ks) {
      h8_t af[2], bfr[4];
#pragma unroll
      for (int mi = 0; mi < 2; ++mi) {
        int row = wm * 32 + mi * 16 + lo;
        int c = (ks * 4 + hi) ^ (row & 7);
        af[mi] = *(const h8_t*)&As[cur][row * 64 + c * 8];
      }
#pragma unroll
      for (int ni = 0; ni < 4; ++ni) {
        int row = wn * 64 + ni * 16 + lo;
        int c = (ks * 4 + hi) ^ (row & 7);
        bfr[ni] = *(const h8_t*)&Bs[cur][row * 64 + c * 8];
      }
#pragma unroll
      for (int mi = 0; mi < 2; ++mi)
#pragma unroll
        for (int ni = 0; ni < 4; ++ni)
          acc[mi][ni] = __builtin_amdgcn_mfma_f32_16x16x32_f16(
              af[mi], bfr[ni], acc[mi][ni], 0, 0, 0);
    }
    if (tt < 63) *(h8_t*)&As[cur ^ 1][aslot] = va2 * (_Float16)fac;
    __syncthreads();
  }

  float bv[4];
#pragma unroll
  for (int ni = 0; ni < 4; ++ni) bv[ni] = bf[wn * 64 + ni * 16 + lo];
#pragma unroll
  for (int mi = 0; mi < 2; ++mi) {
#pragma unroll
    for (int r = 0; r < 4; ++r) {
      int mr = m0 + wm * 32 + mi * 16 + hi * 4 + r;
      if (mr < M) {
#pragma unroll
        for (int ni = 0; ni < 4; ++ni) {
          int n = wn * 64 + ni * 16 + lo;
          float vv = acc[mi][ni][r] + bv[ni];
          if (vv < 0.f) vv = 0.f;
          oH[(size_t)mr * 768 + n] = f2h(vv);
        }
      }
    }
  }
}

// ---------------- aggregation: wave/node, 2 edges per iter, 16B loads ----------------
__global__ __launch_bounds__(256) void k_aggregate(
    const u16* __restrict__ AB, const int* __restrict__ rp,
    const int* __restrict__ col, u16* __restrict__ agg5,
    float* __restrict__ scal3) {
  int w = threadIdx.x >> 6, l = threadIdx.x & 63;
  int n = blockIdx.x * 4 + w;
  int beg = rp[n], end = rp[n + 1];
  int deg = end - beg;
  int half = l >> 5, lf = l & 31;
  float sb[8], qb[8], mnb[8], mxb[8];
#pragma unroll
  for (int j = 0; j < 8; ++j) {
    sb[j] = 0.f; qb[j] = 0.f;
    mnb[j] = 3.402823466e38f; mxb[j] = -3.402823466e38f;
  }
  for (int i = beg + half; i < end; i += 2) {
    int s = col[i];
    h8_t bv = *(const h8_t*)(AB + (size_t)s * 512 + 256 + lf * 8);
#pragma unroll
    for (int j = 0; j < 8; ++j) {
      float b = (float)bv[j];
      sb[j] += b;
      qb[j] = fmaf(b, b, qb[j]);
      mnb[j] = fminf(mnb[j], b);
      mxb[j] = fmaxf(mxb[j], b);
    }
  }
#pragma unroll
  for (int j = 0; j < 8; ++j) {
    sb[j] += __shfl_xor(sb[j], 32, 64);
    qb[j] += __shfl_xor(qb[j], 32, 64);
    mnb[j] = fminf(mnb[j], __shfl_xor(mnb[j], 32, 64));
    mxb[j] = fmaxf(mxb[j], __shfl_xor(mxb[j], 32, 64));
  }
  h8_t cv = *(const h8_t*)(AB + (size_t)n * 512 + lf * 8);
  float degf = (float)deg;
  float degc = degf > 1.f ? degf : 1.f;
  float inv = 1.f / degc;
  float ov[5][8];
#pragma unroll
  for (int j = 0; j < 8; ++j) {
    float c = (float)cv[j];
    float s_m = fmaf(degf, c, sb[j]);
    float mean = s_m * inv;
    float mean2 = fmaf(degf * c, c, fmaf(2.f * c, sb[j], qb[j])) * inv;
    float var = mean2 - mean * mean;
    if (var < 0.f) var = 0.f;
    float sd = sqrtf(var + 1e-5f);
    ov[0][j] = mean;
    ov[1][j] = s_m;
    ov[2][j] = sd;
    ov[3][j] = deg > 0 ? c + mnb[j] : 0.f;
    ov[4][j] = deg > 0 ? c + mxb[j] : 0.f;
  }
  if (half == 0) {
    u16* base = agg5 + (size_t)n * 1280 + lf * 8;
#pragma unroll
    for (int a = 0; a < 5; ++a) {
      h8_t o;
#pragma unroll
      for (int j = 0; j < 8; ++j) o[j] = (_Float16)ov[a][j];
      *(h8_t*)(base + a * 256) = o;
    }
    if (lf == 0) {
      float logd = logf(degc + 1.f);
      float4 sc = make_float4(1.f, logd / AVG_LOG_F, AVG_LOG_F / logd, 0.f);
      *(float4*)(scal3 + (size_t)n * 4) = sc;
    }
  }
}

// bf = Wlin @ bpost + blin (fp32), all 4 (lyr,ch)
__global__ __launch_bounds__(256) void k_bfuse4(
    const float* __restrict__ Wlin_s, const float* __restrict__ Wlin_d,
    const float* __restrict__ bpost_s, const float* __restrict__ bpost_d,
    const float* __restrict__ blin_s, const float* __restrict__ blin_d,
    float* __restrict__ bfv4) {
  __shared__ float bp[256];
  int z = blockIdx.x, lyr = z >> 1, ch = z & 1;
  const float* Wlin = (ch ? Wlin_d : Wlin_s) + (size_t)lyr * 65536;
  const float* bpost = (ch ? bpost_d : bpost_s) + lyr * 256;
  const float* blin = (ch ? blin_d : blin_s) + lyr * 256;
  int t = threadIdx.x;
  bp[t] = bpost[t];
  __syncthreads();
  float s = blin[t];
  for (int k = 0; k < 256; ++k) s = fmaf(Wlin[t * 256 + k], bp[k], s);
  bfv4[z * 256 + t] = s;
}

__global__ __launch_bounds__(256) void k_wout(const u16* __restrict__ x,
                                              const float* __restrict__ w,
                                              const float* __restrict__ b,
                                              float* __restrict__ out, int N) {
  int wid = threadIdx.x >> 6, lane = threadIdx.x & 63;
  int n = blockIdx.x * 4 + wid;
  if (n >= N) return;
  ushort4 xv = *(const ushort4*)(x + (size_t)n * 256 + lane * 4);
  const float4 wv = *(const float4*)(w + lane * 4);
  float s = (float)__builtin_bit_cast(_Float16, xv.x) * wv.x +
            (float)__builtin_bit_cast(_Float16, xv.y) * wv.y +
            (float)__builtin_bit_cast(_Float16, xv.z) * wv.z +
            (float)__builtin_bit_cast(_Float16, xv.w) * wv.w;
#pragma unroll
  for (int off = 32; off > 0; off >>= 1) s += __shfl_down(s, off);
  if (lane == 0) out[n] = s + b[0];
}

extern "C" void kernel_launch(void* const* d_in, const int* in_sizes, int n_in,
                              void* d_out, int out_size, void* d_ws, size_t ws_size,
                              hipStream_t stream) {
  const float* x0      = (const float*)d_in[0];
  const int*   ei_in   = (const int*)d_in[1];
  const int*   ei_out  = (const int*)d_in[2];
  const float* Wpre_s  = (const float*)d_in[3];
  const float* bpre_s  = (const float*)d_in[4];
  const float* Wpost_s = (const float*)d_in[5];
  const float* bpost_s = (const float*)d_in[6];
  const float* Wlin_s  = (const float*)d_in[7];
  const float* blin_s  = (const float*)d_in[8];
  const float* Wpre_d  = (const float*)d_in[9];
  const float* bpre_d  = (const float*)d_in[10];
  const float* Wpost_d = (const float*)d_in[11];
  const float* bpost_d = (const float*)d_in[12];
  const float* Wlin_d  = (const float*)d_in[13];
  const float* blin_d  = (const float*)d_in[14];
  const float* Wcomb   = (const float*)d_in[15];
  const float* bcomb   = (const float*)d_in[16];
  const float* Wout    = (const float*)d_in[17];
  const float* bout    = (const float*)d_in[18];
  float* out = (float*)d_out;

  char* p = (char*)d_ws;
  auto alloc = [&](size_t b) {
    char* r = p;
    p += (b + 255) & ~(size_t)255;
    return r;
  };
  int* deg2     = (int*)alloc((size_t)2 * NN * 4);
  int* cur2     = (int*)alloc((size_t)2 * NN * 4);
  int* rp2      = (int*)alloc((size_t)(2 * NN + 1) * 4);
  int* col2     = (int*)alloc((size_t)2 * NE * 4);
  u16* AB       = (u16*)alloc((size_t)NN * 512 * 2);
  u16* agg52    = (u16*)alloc((size_t)2 * NN * 1280 * 2);
  float* scal32 = (float*)alloc((size_t)2 * NN * 4 * 4);
  u16* xcat1    = (u16*)alloc((size_t)NN * 768 * 2);
  u16* xcat2    = (u16*)alloc((size_t)NN * 768 * 2);
  u16* preS     = (u16*)alloc((size_t)2 * 256 * 512 * 2);
  u16* preD     = (u16*)alloc((size_t)2 * 256 * 512 * 2);
  u16* lincat   = (u16*)alloc((size_t)4 * 256 * 256 * 2);
  u16* combB    = (u16*)alloc((size_t)2 * 256 * 768 * 2);
  u16* Wf4      = (u16*)alloc((size_t)4 * 256 * 4096 * 2);
  float* bfv4   = (float*)alloc((size_t)4 * 256 * 4);
  u16* WpostT4  = (u16*)agg52;  // alias: consumed upfront, before agg52 is written
  u16* xfin     = xcat1;        // alias: xcat1 dead after layer-1 comb

  const int BIG = 1 << 30;

  // upfront converts / CSR / weight folds
  k_cvtw<<<1152, 256, 0, stream>>>(Wpre_s, Wpre_d, Wlin_s, Wlin_d, Wcomb,
                                   preS, preD, lincat, combB);
  k_cvtx<<<5000, 256, 0, stream>>>(x0, xcat1);
  hipMemsetAsync(deg2, 0, (size_t)4 * NN * 4, stream);  // deg2 + cur2 (contiguous)
  k_count2<<<dim3(1250, 2), 256, 0, stream>>>(ei_in, ei_out, deg2, NE);
  k_scan<<<1, 1024, 0, stream>>>(deg2, rp2, 2 * NN);
  k_scatter2<<<dim3(1250, 2), 256, 0, stream>>>(ei_in, ei_out, rp2, cur2, col2, NE);
  k_tc4<<<dim3(128, 8, 4), 256, 0, stream>>>(Wpost_s, Wpost_d, WpostT4);
  // Wf[z] = Wlin[z] @ Wpost[z]  (z = lyr*2+ch), grid covers full chip
  k_mgemm<<<dim3(16, 4, 4), 512, 0, stream>>>(
      lincat, 256, WpostT4, WpostT4, 256, BIG, nullptr,
      Wf4, 4096, 256, 256, 0, 65536, 1048576, 1048576);
  k_bfuse4<<<4, 256, 0, stream>>>(Wlin_s, Wlin_d, bpost_s, bpost_d, blin_s, blin_d, bfv4);

  u16* xcs[2] = {xcat1, xcat2};
  for (int lyr = 0; lyr < 2; ++lyr) {
    u16* xc = xcs[lyr];
    for (int ch = 0; ch < 2; ++ch) {  // ch=0: in-edges ("s"); ch=1: out-edges ("d")
      u16* preW = ch ? preD : preS;
      const float* bpre = ch ? bpre_d : bpre_s;
      // [A | B] = x @ [W1 | W2]^T  -> AB fp16 [NN][512]
      k_mgemm<<<dim3(2, 313, 1), 512, 0, stream>>>(
          xc, 768, preW + (size_t)lyr * 131072, preW + (size_t)lyr * 131072 + 256,
          512, 256, bpre + (size_t)lyr * 256,
          AB, 512, NN, 256, 0, 0, 0, 0);
      k_aggregate<<<5000, 256, 0, stream>>>(
          AB, rp2 + ch * NN, col2,
          agg52 + (size_t)ch * NN * 1280, scal32 + (size_t)ch * NN * 4);
    }
    // h_{s,d} = relu(V @ Wf^T + bf) -> xc cols [256:512) and [512:768)
    k_pgemm<<<dim3(313, 2), 512, 0, stream>>>(
        xc, agg52, scal32, Wf4 + (size_t)lyr * 2 * 1048576, bfv4 + lyr * 512, xc, NN);
    // x_next = relu([x, h_in, h_out] @ Wcomb^T + bcomb)
    if (lyr == 0) {
      k_mgemm<<<dim3(1, 313, 1), 512, 0, stream>>>(
          xc, 768, combB, combB, 768, BIG, bcomb,
          xcat2, 768, NN, 768, 1, 0, 0, 0);
    } else {
      k_mgemm<<<dim3(1, 313, 1), 512, 0, stream>>>(
          xc, 768, combB + 196608, combB + 196608, 768, BIG, bcomb + 256,
          xfin, 256, NN, 768, 1, 0, 0, 0);
    }
  }
  k_wout<<<5000, 256, 0, stream>>>(xfin, Wout, bout, out, NN);
}

// Round 10
// 807.923 us; speedup vs baseline: 5.8067x; 1.0550x over previous
//
#include <hip/hip_runtime.h>
#include <math.h>

#define NN 20000
#define NE 320000
#define AVG_LOG_F 2.83321334f

typedef unsigned short u16;
typedef _Float16 h8_t __attribute__((ext_vector_type(8)));
typedef float f4_t __attribute__((ext_vector_type(4)));

__device__ __forceinline__ u16 f2h(float f) {
  _Float16 h = (_Float16)f;
  return __builtin_bit_cast(u16, h);
}
__device__ __forceinline__ void gld16(const void* g, void* l) {
  __builtin_amdgcn_global_load_lds(
      (const __attribute__((address_space(1))) void*)g,
      (__attribute__((address_space(3))) void*)l, 16, 0, 0);
}

// ---------------- CSR build (both channels in one pass) ----------------
__global__ __launch_bounds__(256) void k_count2(const int* __restrict__ ein,
                                                const int* __restrict__ eout,
                                                int* __restrict__ deg2, int E) {
  int e = blockIdx.x * 256 + threadIdx.x;
  int ch = blockIdx.y;
  const int* dst = (ch ? eout : ein) + E;
  if (e < E) atomicAdd(&deg2[ch * NN + dst[e]], 1);
}

__global__ __launch_bounds__(1024) void k_scan(const int* __restrict__ deg,
                                               int* __restrict__ rp, int N) {
  __shared__ int lds[1024];
  int t = threadIdx.x;
  int CH = (N + 1023) >> 10;
  int base = t * CH;
  int s = 0;
  for (int i = 0; i < CH; ++i) { int idx = base + i; if (idx < N) s += deg[idx]; }
  lds[t] = s;
  __syncthreads();
  for (int off = 1; off < 1024; off <<= 1) {
    int v = (t >= off) ? lds[t - off] : 0;
    __syncthreads();
    lds[t] += v;
    __syncthreads();
  }
  int run = (t == 0) ? 0 : lds[t - 1];
  for (int i = 0; i < CH; ++i) {
    int idx = base + i;
    if (idx < N) { rp[idx] = run; run += deg[idx]; }
  }
  if (t == 1023) rp[N] = run;
}

__global__ __launch_bounds__(256) void k_scatter2(const int* __restrict__ ein,
                                                  const int* __restrict__ eout,
                                                  const int* __restrict__ rp2,
                                                  int* __restrict__ cur2,
                                                  int* __restrict__ col2, int E) {
  int e = blockIdx.x * 256 + threadIdx.x;
  int ch = blockIdx.y;
  const int* src = (ch ? eout : ein);
  const int* dst = src + E;
  if (e < E) {
    int d = dst[e];
    int p = atomicAdd(&cur2[ch * NN + d], 1);
    col2[rp2[ch * NN + d] + p] = src[e];
  }
}

// ---------------- converts ----------------
// merged weight convert. pre2 layout: [(lyr*2+ch)][256][512] fp16.
__global__ __launch_bounds__(256) void k_cvtw(
    const float* __restrict__ Wpre_s, const float* __restrict__ Wpre_d,
    const float* __restrict__ Wlin_s, const float* __restrict__ Wlin_d,
    const float* __restrict__ Wcomb,
    u16* __restrict__ pre2, u16* __restrict__ lincat, u16* __restrict__ combB) {
  int i = blockIdx.x * 256 + threadIdx.x;  // float4 index
  const float* src;
  u16* dst;
  int so, dofs;
  if (i < 65536)       { int j = i; int lyr = j >> 15;
                         src = Wpre_s; dst = pre2; so = j;
                         dofs = (lyr * 2 + 0) * 32768 + (j & 32767); }
  else if (i < 131072) { int j = i - 65536; int lyr = j >> 15;
                         src = Wpre_d; dst = pre2; so = j;
                         dofs = (lyr * 2 + 1) * 32768 + (j & 32767); }
  else if (i < 163840) { int j = i - 131072; int lyr = j >> 14;
                         src = Wlin_s; dst = lincat; so = j; dofs = j + lyr * 16384; }
  else if (i < 196608) { int j = i - 163840; int lyr = j >> 14;
                         src = Wlin_d; dst = lincat; so = j; dofs = j + (lyr + 1) * 16384; }
  else if (i < 294912) { src = Wcomb; dst = combB; so = i - 196608; dofs = so; }
  else return;
  float4 v = *(const float4*)(src + (size_t)so * 4);
  ushort4 o;
  o.x = f2h(v.x); o.y = f2h(v.y); o.z = f2h(v.z); o.w = f2h(v.w);
  *(ushort4*)(dst + (size_t)dofs * 4) = o;
}

// x0 -> xcat1[:,0:256] (ld 768); also bpre4 concat (tiny, first blocks)
__global__ __launch_bounds__(256) void k_cvtx(const float* __restrict__ x,
                                              u16* __restrict__ xc,
                                              const float* __restrict__ bpre_s,
                                              const float* __restrict__ bpre_d,
                                              float* __restrict__ bpre4) {
  int i = blockIdx.x * 256 + threadIdx.x;  // over NN*64
  int row = i >> 6, c = (i & 63) * 4;
  float4 v = *(const float4*)(x + (size_t)row * 256 + c);
  ushort4 o;
  o.x = f2h(v.x); o.y = f2h(v.y); o.z = f2h(v.z); o.w = f2h(v.w);
  *(ushort4*)(xc + (size_t)row * 768 + c) = o;
  if (i < 1024) {
    // bpre4[(lyr*2+ch)*256 + n]
    int z = i >> 8, n = i & 255;
    int lyr = z >> 1, ch = z & 1;
    bpre4[i] = (ch ? bpre_d : bpre_s)[lyr * 256 + n];
  }
}

// transpose-convert Wpost [256,4096] f32 -> [4096,256] fp16, all 4 (lyr,ch)
__global__ __launch_bounds__(256) void k_tc4(const float* __restrict__ Ws,
                                             const float* __restrict__ Wd,
                                             u16* __restrict__ outT) {
  __shared__ float tile[32][33];
  int z = blockIdx.z;
  const float* in = ((z & 1) ? Wd : Ws) + (size_t)(z >> 1) * 256 * 4096;
  u16* out = outT + (size_t)z * (4096 * 256);
  int bx = blockIdx.x, by = blockIdx.y;
  int r = threadIdx.x >> 5, c = threadIdx.x & 31;
#pragma unroll
  for (int it = 0; it < 4; ++it)
    tile[r + it * 8][c] = in[(size_t)(by * 32 + r + it * 8) * 4096 + bx * 32 + c];
  __syncthreads();
#pragma unroll
  for (int it = 0; it < 4; ++it)
    out[(size_t)(bx * 32 + r + it * 8) * 256 + by * 32 + c] = f2h(tile[c][r + it * 8]);
}

// ---------------- MFMA fp16 GEMM, double-buffered (pre/Wf/comb) ----------------
// bias indexed with z stride zBias.
__global__ __launch_bounds__(512) void k_mgemm(
    const u16* __restrict__ A, int lda,
    const u16* __restrict__ B, const u16* __restrict__ B2, int ldb, int nsplit,
    const float* __restrict__ bias, int zBias,
    u16* __restrict__ oH, int ldoH,
    int M, int K, int relu, int zA, int zB, int zO) {
  __shared__ u16 As[2][64 * 64];
  __shared__ u16 Bs[2][256 * 64];
  const int t = threadIdx.x;
  const int z = blockIdx.z;
  A += (size_t)z * zA;
  B += (size_t)z * zB;
  B2 += (size_t)z * zB;
  oH += (size_t)z * zO;
  if (bias) bias += (size_t)z * zBias;
  const int m0 = blockIdx.y * 64;
  const int n0 = blockIdx.x * 256;
  const int l = t & 63, w = t >> 6;
  const int wm = w >> 2, wn = w & 3;
  const int lo = l & 15, hi = l >> 4;

  f4_t acc[2][4];
#pragma unroll
  for (int i = 0; i < 2; ++i)
#pragma unroll
    for (int j = 0; j < 4; ++j) acc[i][j] = (f4_t)0.f;

  const int ra = t >> 3, pa = t & 7;
  const int la = pa ^ (ra & 7);
  int rra = m0 + ra;
  if (rra > M - 1) rra = M - 1;
  const u16* gA = A + (size_t)rra * lda + la * 8;

  const u16* gB[4];
  int lBo[4];
#pragma unroll
  for (int i = 0; i < 4; ++i) {
    int q = i * 512 + t;
    int r = q >> 3, p2 = q & 7;
    int lc = p2 ^ (r & 7);
    int n = n0 + r;
    const u16* bp = (n < nsplit) ? (B + (size_t)n * ldb) : (B2 + (size_t)(n - nsplit) * ldb);
    gB[i] = bp + lc * 8;
    lBo[i] = q * 8;
  }

  gld16(gA, &As[0][t * 8]);
#pragma unroll
  for (int i = 0; i < 4; ++i) gld16(gB[i], &Bs[0][lBo[i]]);
  __syncthreads();

  const int nt = K >> 6;
  for (int tt = 0; tt < nt; ++tt) {
    const int cur = tt & 1;
    if (tt + 1 < nt) {
      const int ko = (tt + 1) << 6;
      gld16(gA + ko, &As[cur ^ 1][t * 8]);
#pragma unroll
      for (int i = 0; i < 4; ++i) gld16(gB[i] + ko, &Bs[cur ^ 1][lBo[i]]);
    }
#pragma unroll
    for (int ks = 0; ks < 2; ++ks) {
      h8_t af[2], bfr[4];
#pragma unroll
      for (int mi = 0; mi < 2; ++mi) {
        int row = wm * 32 + mi * 16 + lo;
        int c = (ks * 4 + hi) ^ (row & 7);
        af[mi] = *(const h8_t*)&As[cur][row * 64 + c * 8];
      }
#pragma unroll
      for (int ni = 0; ni < 4; ++ni) {
        int row = wn * 64 + ni * 16 + lo;
        int c = (ks * 4 + hi) ^ (row & 7);
        bfr[ni] = *(const h8_t*)&Bs[cur][row * 64 + c * 8];
      }
#pragma unroll
      for (int mi = 0; mi < 2; ++mi)
#pragma unroll
        for (int ni = 0; ni < 4; ++ni)
          acc[mi][ni] = __builtin_amdgcn_mfma_f32_16x16x32_f16(
              af[mi], bfr[ni], acc[mi][ni], 0, 0, 0);
    }
    __syncthreads();
  }

  float bv[4];
#pragma unroll
  for (int ni = 0; ni < 4; ++ni) {
    int n = n0 + wn * 64 + ni * 16 + lo;
    bv[ni] = (n < nsplit) ? (bias ? bias[n] : 0.f) : 0.f;
  }
#pragma unroll
  for (int mi = 0; mi < 2; ++mi) {
#pragma unroll
    for (int r = 0; r < 4; ++r) {
      int m = m0 + wm * 32 + mi * 16 + hi * 4 + r;
      if (m < M) {
#pragma unroll
        for (int ni = 0; ni < 4; ++ni) {
          int n = n0 + wn * 64 + ni * 16 + lo;
          float v = acc[mi][ni][r] + bv[ni];
          if (relu && v < 0.f) v = 0.f;
          oH[(size_t)m * ldoH + n] = f2h(v);
        }
      }
    }
  }
}

// ---------------- post GEMM: PROVEN round-2 structure, channel-merged grid ----------------
// virtual A = [x | agg | agg*s1 | agg*s2] (K=4096); B = Wf[ch]; out fp16 into xc cols.
// 64x256 tile, 512 threads, single-buffer 2-barrier loop. ch = blockIdx.y.
__global__ __launch_bounds__(512) void k_pgemm(
    const u16* __restrict__ xc, const u16* __restrict__ agg5c,
    const float* __restrict__ scal3c, const u16* __restrict__ Wfl,
    const float* __restrict__ bfl, u16* __restrict__ oHb, int M) {
  __shared__ u16 As[64 * 64];
  __shared__ u16 Bs[256 * 64];
  const int t = threadIdx.x;
  const int ch = blockIdx.y;
  const u16* agg5 = agg5c + (size_t)ch * NN * 1280;
  const float* scal3 = scal3c + (size_t)ch * NN * 4;
  const u16* Wf = Wfl + (size_t)ch * (256 * 4096);
  const float* bf = bfl + ch * 256;
  u16* oH = oHb + 256 + ch * 256;  // ldoH = 768
  const int m0 = blockIdx.x * 64;
  const int l = t & 63, w = t >> 6;
  const int wm = w >> 2, wn = w & 3;
  const int lo = l & 15, hi = l >> 4;

  f4_t acc[2][4];
#pragma unroll
  for (int i = 0; i < 2; ++i)
#pragma unroll
    for (int j = 0; j < 4; ++j) acc[i][j] = (f4_t)0.f;

  // A reg-staging: thread -> row ra, k-chunk pa (8 fp16); swizzled LDS slot
  const int ra = t >> 3, pa = t & 7;
  int m = m0 + ra;
  if (m > M - 1) m = M - 1;
  u16* ldA = &As[ra * 64 + (pa ^ (ra & 7)) * 8];
  const u16* xrow = xc + (size_t)m * 768;
  const u16* arow = agg5 + (size_t)m * 1280;
  const float* srow = scal3 + (size_t)m * 4;

  // B: direct global->LDS, pre-swizzled source (n0==0, Nout=256)
  const u16* gB[4];
  u16* lB[4];
#pragma unroll
  for (int i = 0; i < 4; ++i) {
    int q = i * 512 + t;
    int r = q >> 3, p2 = q & 7;
    int lc = p2 ^ (r & 7);
    gB[i] = Wf + (size_t)r * 4096 + lc * 8;
    lB[i] = &Bs[q * 8];
  }

  for (int k0 = 0; k0 < 4096; k0 += 64) {
#pragma unroll
    for (int i = 0; i < 4; ++i) gld16(gB[i] + k0, lB[i]);
    int k = k0 + pa * 8;
    h8_t v;
    if (k < 256) {
      v = *(const h8_t*)(xrow + k);
    } else {
      int q = k - 256;
      int g = q / 1280;
      int r2 = q - g * 1280;
      v = *(const h8_t*)(arow + r2);
      v = v * (_Float16)srow[g];
    }
    *(h8_t*)ldA = v;
    __syncthreads();
#pragma unroll
    for (int ks = 0; ks < 2; ++ks) {
      h8_t af[2], bfr[4];
#pragma unroll
      for (int mi = 0; mi < 2; ++mi) {
        int row = wm * 32 + mi * 16 + lo;
        int c = (ks * 4 + hi) ^ (row & 7);
        af[mi] = *(const h8_t*)&As[row * 64 + c * 8];
      }
#pragma unroll
      for (int ni = 0; ni < 4; ++ni) {
        int row = wn * 64 + ni * 16 + lo;
        int c = (ks * 4 + hi) ^ (row & 7);
        bfr[ni] = *(const h8_t*)&Bs[row * 64 + c * 8];
      }
#pragma unroll
      for (int mi = 0; mi < 2; ++mi)
#pragma unroll
        for (int ni = 0; ni < 4; ++ni)
          acc[mi][ni] = __builtin_amdgcn_mfma_f32_16x16x32_f16(
              af[mi], bfr[ni], acc[mi][ni], 0, 0, 0);
    }
    __syncthreads();
  }

  float bv[4];
#pragma unroll
  for (int ni = 0; ni < 4; ++ni) bv[ni] = bf[wn * 64 + ni * 16 + lo];
#pragma unroll
  for (int mi = 0; mi < 2; ++mi) {
#pragma unroll
    for (int r = 0; r < 4; ++r) {
      int mr = m0 + wm * 32 + mi * 16 + hi * 4 + r;
      if (mr < M) {
#pragma unroll
        for (int ni = 0; ni < 4; ++ni) {
          int n = wn * 64 + ni * 16 + lo;
          float vv = acc[mi][ni][r] + bv[ni];
          if (vv < 0.f) vv = 0.f;
          oH[(size_t)mr * 768 + n] = f2h(vv);
        }
      }
    }
  }
}

// ---------------- aggregation: both channels, wave/node, 16B loads ----------------
__global__ __launch_bounds__(256) void k_aggregate(
    const u16* __restrict__ AB2, const int* __restrict__ rp2,
    const int* __restrict__ col2, u16* __restrict__ agg52,
    float* __restrict__ scal32) {
  int ch = blockIdx.y;
  const u16* AB = AB2 + (size_t)ch * NN * 512;
  const int* rp = rp2 + ch * NN;
  u16* agg5 = agg52 + (size_t)ch * NN * 1280;
  float* scal3 = scal32 + (size_t)ch * NN * 4;
  int w = threadIdx.x >> 6, l = threadIdx.x & 63;
  int n = blockIdx.x * 4 + w;
  int beg = rp[n], end = rp[n + 1];
  int deg = end - beg;
  int half = l >> 5, lf = l & 31;
  float sb[8], qb[8], mnb[8], mxb[8];
#pragma unroll
  for (int j = 0; j < 8; ++j) {
    sb[j] = 0.f; qb[j] = 0.f;
    mnb[j] = 3.402823466e38f; mxb[j] = -3.402823466e38f;
  }
  for (int i = beg + half; i < end; i += 2) {
    int s = col2[i];
    h8_t bv = *(const h8_t*)(AB + (size_t)s * 512 + 256 + lf * 8);
#pragma unroll
    for (int j = 0; j < 8; ++j) {
      float b = (float)bv[j];
      sb[j] += b;
      qb[j] = fmaf(b, b, qb[j]);
      mnb[j] = fminf(mnb[j], b);
      mxb[j] = fmaxf(mxb[j], b);
    }
  }
#pragma unroll
  for (int j = 0; j < 8; ++j) {
    sb[j] += __shfl_xor(sb[j], 32, 64);
    qb[j] += __shfl_xor(qb[j], 32, 64);
    mnb[j] = fminf(mnb[j], __shfl_xor(mnb[j], 32, 64));
    mxb[j] = fmaxf(mxb[j], __shfl_xor(mxb[j], 32, 64));
  }
  h8_t cv = *(const h8_t*)(AB + (size_t)n * 512 + lf * 8);
  float degf = (float)deg;
  float degc = degf > 1.f ? degf : 1.f;
  float inv = 1.f / degc;
  float ov[5][8];
#pragma unroll
  for (int j = 0; j < 8; ++j) {
    float c = (float)cv[j];
    float s_m = fmaf(degf, c, sb[j]);
    float mean = s_m * inv;
    float mean2 = fmaf(degf * c, c, fmaf(2.f * c, sb[j], qb[j])) * inv;
    float var = mean2 - mean * mean;
    if (var < 0.f) var = 0.f;
    float sd = sqrtf(var + 1e-5f);
    ov[0][j] = mean;
    ov[1][j] = s_m;
    ov[2][j] = sd;
    ov[3][j] = deg > 0 ? c + mnb[j] : 0.f;
    ov[4][j] = deg > 0 ? c + mxb[j] : 0.f;
  }
  if (half == 0) {
    u16* base = agg5 + (size_t)n * 1280 + lf * 8;
#pragma unroll
    for (int a = 0; a < 5; ++a) {
      h8_t o;
#pragma unroll
      for (int j = 0; j < 8; ++j) o[j] = (_Float16)ov[a][j];
      *(h8_t*)(base + a * 256) = o;
    }
    if (lf == 0) {
      float logd = logf(degc + 1.f);
      float4 sc = make_float4(1.f, logd / AVG_LOG_F, AVG_LOG_F / logd, 0.f);
      *(float4*)(scal3 + (size_t)n * 4) = sc;
    }
  }
}

// bf = Wlin @ bpost + blin (fp32), all 4 (lyr,ch)
__global__ __launch_bounds__(256) void k_bfuse4(
    const float* __restrict__ Wlin_s, const float* __restrict__ Wlin_d,
    const float* __restrict__ bpost_s, const float* __restrict__ bpost_d,
    const float* __restrict__ blin_s, const float* __restrict__ blin_d,
    float* __restrict__ bfv4) {
  __shared__ float bp[256];
  int z = blockIdx.x, lyr = z >> 1, ch = z & 1;
  const float* Wlin = (ch ? Wlin_d : Wlin_s) + (size_t)lyr * 65536;
  const float* bpost = (ch ? bpost_d : bpost_s) + lyr * 256;
  const float* blin = (ch ? blin_d : blin_s) + lyr * 256;
  int t = threadIdx.x;
  bp[t] = bpost[t];
  __syncthreads();
  float s = blin[t];
  for (int k = 0; k < 256; ++k) s = fmaf(Wlin[t * 256 + k], bp[k], s);
  bfv4[z * 256 + t] = s;
}

__global__ __launch_bounds__(256) void k_wout(const u16* __restrict__ x,
                                              const float* __restrict__ w,
                                              const float* __restrict__ b,
                                              float* __restrict__ out, int N) {
  int wid = threadIdx.x >> 6, lane = threadIdx.x & 63;
  int n = blockIdx.x * 4 + wid;
  if (n >= N) return;
  ushort4 xv = *(const ushort4*)(x + (size_t)n * 256 + lane * 4);
  const float4 wv = *(const float4*)(w + lane * 4);
  float s = (float)__builtin_bit_cast(_Float16, xv.x) * wv.x +
            (float)__builtin_bit_cast(_Float16, xv.y) * wv.y +
            (float)__builtin_bit_cast(_Float16, xv.z) * wv.z +
            (float)__builtin_bit_cast(_Float16, xv.w) * wv.w;
#pragma unroll
  for (int off = 32; off > 0; off >>= 1) s += __shfl_down(s, off);
  if (lane == 0) out[n] = s + b[0];
}

extern "C" void kernel_launch(void* const* d_in, const int* in_sizes, int n_in,
                              void* d_out, int out_size, void* d_ws, size_t ws_size,
                              hipStream_t stream) {
  const float* x0      = (const float*)d_in[0];
  const int*   ei_in   = (const int*)d_in[1];
  const int*   ei_out  = (const int*)d_in[2];
  const float* Wpre_s  = (const float*)d_in[3];
  const float* bpre_s  = (const float*)d_in[4];
  const float* Wpost_s = (const float*)d_in[5];
  const float* bpost_s = (const float*)d_in[6];
  const float* Wlin_s  = (const float*)d_in[7];
  const float* blin_s  = (const float*)d_in[8];
  const float* Wpre_d  = (const float*)d_in[9];
  const float* bpre_d  = (const float*)d_in[10];
  const float* Wpost_d = (const float*)d_in[11];
  const float* bpost_d = (const float*)d_in[12];
  const float* Wlin_d  = (const float*)d_in[13];
  const float* blin_d  = (const float*)d_in[14];
  const float* Wcomb   = (const float*)d_in[15];
  const float* bcomb   = (const float*)d_in[16];
  const float* Wout    = (const float*)d_in[17];
  const float* bout    = (const float*)d_in[18];
  float* out = (float*)d_out;

  char* p = (char*)d_ws;
  auto alloc = [&](size_t b) {
    char* r = p;
    p += (b + 255) & ~(size_t)255;
    return r;
  };
  int* deg2     = (int*)alloc((size_t)2 * NN * 4);
  int* cur2     = (int*)alloc((size_t)2 * NN * 4);
  int* rp2      = (int*)alloc((size_t)(2 * NN + 1) * 4);
  int* col2     = (int*)alloc((size_t)2 * NE * 4);
  u16* AB2      = (u16*)alloc((size_t)2 * NN * 512 * 2);
  u16* agg52    = (u16*)alloc((size_t)2 * NN * 1280 * 2);
  float* scal32 = (float*)alloc((size_t)2 * NN * 4 * 4);
  u16* xcat1    = (u16*)alloc((size_t)NN * 768 * 2);
  u16* xcat2    = (u16*)alloc((size_t)NN * 768 * 2);
  u16* pre2     = (u16*)alloc((size_t)4 * 256 * 512 * 2);
  u16* lincat   = (u16*)alloc((size_t)4 * 256 * 256 * 2);
  u16* combB    = (u16*)alloc((size_t)2 * 256 * 768 * 2);
  u16* Wf4      = (u16*)alloc((size_t)4 * 256 * 4096 * 2);
  float* bfv4   = (float*)alloc((size_t)4 * 256 * 4);
  float* bpre4  = (float*)alloc((size_t)4 * 256 * 4);
  u16* WpostT4  = (u16*)agg52;  // alias: consumed upfront, before agg52 is written
  u16* xfin     = xcat1;        // alias: xcat1 dead after layer-1 comb

  const int BIG = 1 << 30;

  k_cvtw<<<1152, 256, 0, stream>>>(Wpre_s, Wpre_d, Wlin_s, Wlin_d, Wcomb,
                                   pre2, lincat, combB);
  k_cvtx<<<5000, 256, 0, stream>>>(x0, xcat1, bpre_s, bpre_d, bpre4);
  hipMemsetAsync(deg2, 0, (size_t)4 * NN * 4, stream);  // deg2 + cur2 (contiguous)
  k_count2<<<dim3(1250, 2), 256, 0, stream>>>(ei_in, ei_out, deg2, NE);
  k_scan<<<1, 1024, 0, stream>>>(deg2, rp2, 2 * NN);
  k_scatter2<<<dim3(1250, 2), 256, 0, stream>>>(ei_in, ei_out, rp2, cur2, col2, NE);
  k_tc4<<<dim3(128, 8, 4), 256, 0, stream>>>(Wpost_s, Wpost_d, WpostT4);
  k_mgemm<<<dim3(16, 4, 4), 512, 0, stream>>>(
      lincat, 256, WpostT4, WpostT4, 256, BIG, nullptr, 0,
      Wf4, 4096, 256, 256, 0, 65536, 1048576, 1048576);
  k_bfuse4<<<4, 256, 0, stream>>>(Wlin_s, Wlin_d, bpost_s, bpost_d, blin_s, blin_d, bfv4);

  u16* xcs[2] = {xcat1, xcat2};
  for (int lyr = 0; lyr < 2; ++lyr) {
    u16* xc = xcs[lyr];
    // [A | B] = x @ [W1 | W2]^T for both channels (z) -> AB2 fp16 [2][NN][512]
    k_mgemm<<<dim3(2, 313, 2), 512, 0, stream>>>(
        xc, 768, pre2 + (size_t)lyr * 2 * 131072, pre2 + (size_t)lyr * 2 * 131072 + 256,
        512, 256, bpre4 + (size_t)lyr * 2 * 256, 256,
        AB2, 512, NN, 256, 0, 0, 131072, NN * 512);
    k_aggregate<<<dim3(5000, 2), 256, 0, stream>>>(AB2, rp2, col2, agg52, scal32);
    // h_{s,d} = relu(V @ Wf^T + bf) -> xc cols [256:512) and [512:768)
    k_pgemm<<<dim3(313, 2), 512, 0, stream>>>(
        xc, agg52, scal32, Wf4 + (size_t)lyr * 2 * 1048576, bfv4 + lyr * 512, xc, NN);
    // x_next = relu([x, h_in, h_out] @ Wcomb^T + bcomb)
    if (lyr == 0) {
      k_mgemm<<<dim3(1, 313, 1), 512, 0, stream>>>(
          xc, 768, combB, combB, 768, BIG, bcomb, 0,
          xcat2, 768, NN, 768, 1, 0, 0, 0);
    } else {
      k_mgemm<<<dim3(1, 313, 1), 512, 0, stream>>>(
          xc, 768, combB + 196608, combB + 196608, 768, BIG, bcomb + 256, 0,
          xfin, 256, NN, 768, 1, 0, 0, 0);
    }
  }
  k_wout<<<5000, 256, 0, stream>>>(xfin, Wout, bout, out, NN);
}